// Round 9
// baseline (256.481 us; speedup 1.0000x reference)
//
#include <hip/hip_runtime.h>
#include <hip/hip_bf16.h>

#define D 128
#define BSH 8                      // 256 nodes per bucket
#define BMASK 255
#define CSTRIDE 32                 // bucket cursors padded to 1 per 128B line

typedef __attribute__((ext_vector_type(8))) short bf16x8;
typedef __attribute__((ext_vector_type(4))) float f32x4;
typedef unsigned short u16;
typedef unsigned int u32;
typedef unsigned long long u64;

// fp32 -> bf16 RNE via gfx950 v_cvt_pk_bf16_f32 (no builtin; T12 recipe).
// Same rounding as the old bit-math (add 0x7FFF + lsb), 1 VALU instead of ~4.
__device__ inline u16 f2bf(float f) {
    u32 r;
    asm("v_cvt_pk_bf16_f32 %0, %1, %1" : "=v"(r) : "v"(f));
    return (u16)r;
}
// pack two f32 -> (bf16(lo) | bf16(hi)<<16) in one instruction
__device__ inline u32 pk2bf(float lo, float hi) {
    u32 r;
    asm("v_cvt_pk_bf16_f32 %0, %1, %2" : "=v"(r) : "v"(lo), "v"(hi));
    return r;
}

// ---------------------------------------------------------------------------
// fp32 -> bf16 cast of three arrays + bucket-cursor init, one launch.
// ---------------------------------------------------------------------------
__global__ void cast3_kernel(const float* __restrict__ a, const float* __restrict__ b,
                             const float* __restrict__ c, u16* __restrict__ oa,
                             u16* __restrict__ ob, u16* __restrict__ oc,
                             int na4, int nw4,
                             int* __restrict__ bCursor, int nbuk, int cap) {
    int i = blockIdx.x * blockDim.x + threadIdx.x;
    if (i < nbuk) bCursor[i * CSTRIDE] = i * cap;    // fixed-stride bucket bases
    const float* in; u16* out; int k;
    if (i < na4)                { in = a; out = oa; k = i; }
    else if (i < na4 + nw4)     { in = b; out = ob; k = i - na4; }
    else if (i < na4 + 2 * nw4) { in = c; out = oc; k = i - na4 - nw4; }
    else return;
    float4 v = *(const float4*)(in + (size_t)k * 4);
    *(uint2*)(out + (size_t)k * 4) = make_uint2(pk2bf(v.x, v.y), pk2bf(v.z, v.w));
}

// ---------------------------------------------------------------------------
// Partition edges into fixed-stride buckets (bucket b owns temp[b*cap ..)).
// 1024 threads/block (16 waves/CU) to cover strided-load latency.
// ---------------------------------------------------------------------------
__global__ void __launch_bounds__(1024)
partition_kernel(const int* __restrict__ src, const int* __restrict__ dst,
                 const float* __restrict__ w, int* __restrict__ bucketCursor,
                 uint2* __restrict__ temp, int E, int nbuk) {
    __shared__ int cnt[1024];
    __shared__ int base[1024];
    int per = (E + gridDim.x - 1) / gridDim.x;
    int lo = blockIdx.x * per;
    int hi = min(E, lo + per);
    for (int i = threadIdx.x; i < nbuk; i += blockDim.x) cnt[i] = 0;
    __syncthreads();
    for (int i = lo + threadIdx.x; i < hi; i += blockDim.x)
        atomicAdd(&cnt[src[i] >> BSH], 1);
    __syncthreads();
    for (int i = threadIdx.x; i < nbuk; i += blockDim.x)
        base[i] = cnt[i] ? atomicAdd(&bucketCursor[i * CSTRIDE], cnt[i]) : 0;
    __syncthreads();
    for (int i = threadIdx.x; i < nbuk; i += blockDim.x) cnt[i] = 0;
    __syncthreads();
    for (int i = lo + threadIdx.x; i < hi; i += blockDim.x) {
        int s = src[i];
        int b = s >> BSH;
        int off = atomicAdd(&cnt[b], 1);
        temp[base[b] + off] =
            make_uint2((u32)dst[i] | ((u32)(s & BMASK) << 17), __float_as_uint(w[i]));
    }
}

// ---------------------------------------------------------------------------
// Per-bucket CSR finalize. 1024 threads/block; scan sections guarded t<256.
// ---------------------------------------------------------------------------
__global__ void __launch_bounds__(1024)
bucket_csr(const uint2* __restrict__ temp, const int* __restrict__ bucketEnd,
           uint2* __restrict__ rowse, uint2* __restrict__ edge,
           int N, int cap) {
    int b = blockIdx.x;
    int lo = b * cap;
    int hi = bucketEnd[b * CSTRIDE];
    int t = threadIdx.x;
    __shared__ int deg_l[256];
    __shared__ int sc[256];
    __shared__ int cur[256];
    if (t < 256) deg_l[t] = 0;
    __syncthreads();
    for (int i = lo + t; i < hi; i += 1024)
        atomicAdd(&deg_l[temp[i].x >> 17], 1);
    __syncthreads();
    int mydeg = (t < 256) ? deg_l[t] : 0;
    if (t < 256) sc[t] = mydeg;
    __syncthreads();
    for (int off = 1; off < 256; off <<= 1) {
        int v = 0;
        if (t < 256 && t >= off) v = sc[t - off];
        __syncthreads();
        if (t < 256) sc[t] += v;
        __syncthreads();
    }
    if (t < 256) {
        int excl = (t == 0) ? 0 : sc[t - 1];
        int gnode = (b << BSH) + t;
        if (gnode < N) rowse[gnode] = make_uint2((u32)(lo + excl), (u32)mydeg);
        cur[t] = excl;
    }
    __syncthreads();
    for (int i = lo + t; i < hi; i += 1024) {
        uint2 r = temp[i];                     // L2-hot
        int p = atomicAdd(&cur[r.x >> 17], 1);
        edge[lo + p] = make_uint2(r.x & 0x1FFFFu, r.y);
    }
}

// ---------------------------------------------------------------------------
// Gather aggregation v3: lane-group gather (4 groups x 16 lanes, one VMEM
// covers 4 edges' 256B rows) + cvt_pk epilogue + nontemporal edge-record
// loads (read-once 6.4MB stream; stop evicting feat rows from L2).
// ---------------------------------------------------------------------------
__global__ void aggregate_kernel(const u16* __restrict__ feat,
                                 const uint2* __restrict__ rowse,
                                 const uint2* __restrict__ edge,
                                 u16* __restrict__ neigh, int n) {
    const char* fb = (const char*)feat;
    const u64* edge64 = (const u64*)edge;
    int wv   = blockIdx.x * 4 + (threadIdx.x >> 6);
    int lane = threadIdx.x & 63;
    int grp  = lane >> 4;          // edge slot within wave
    int l16  = lane & 15;          // owns dims l16*8 .. l16*8+7
    int node0 = wv * 4;
    if (node0 >= n) return;

    int begs[4], degs[4];
#pragma unroll
    for (int i = 0; i < 4; ++i) {
        int nd = node0 + i; if (nd > n - 1) nd = n - 1;
        uint2 se = rowse[nd];
        begs[i] = __builtin_amdgcn_readfirstlane((int)se.x);
        degs[i] = __builtin_amdgcn_readfirstlane((int)se.y);
    }

#pragma unroll 1
    for (int i = 0; i < 4; ++i) {
        int node = node0 + i;
        if (node >= n) break;
        int beg = begs[i];
        int end = beg + degs[i];
        float acc[8] = {0.f, 0.f, 0.f, 0.f, 0.f, 0.f, 0.f, 0.f};
        float ws = 0.f;
        for (int j = beg; j < end; j += 8) {
            int ia = j + grp;
            int ib = j + 4 + grp;
            int ca = ia < end ? ia : end - 1;    // deg==0 never enters loop
            int cb = ib < end ? ib : end - 1;
            u64 pa = __builtin_nontemporal_load(edge64 + ca);
            u64 pb = __builtin_nontemporal_load(edge64 + cb);
            u32 eax = (u32)pa;           // dst index
            u32 ebx = (u32)pb;
            float wa = (ia < end) ? __uint_as_float((u32)(pa >> 32)) : 0.f;
            float wb = (ib < end) ? __uint_as_float((u32)(pb >> 32)) : 0.f;
            uint4 ua = *(const uint4*)(fb + (size_t)eax * 256u + (u32)l16 * 16u);
            uint4 ub = *(const uint4*)(fb + (size_t)ebx * 256u + (u32)l16 * 16u);
            u32 va[4] = {ua.x, ua.y, ua.z, ua.w};
            u32 vb[4] = {ub.x, ub.y, ub.z, ub.w};
#pragma unroll
            for (int kk = 0; kk < 4; ++kk) {
                acc[kk * 2]     += __uint_as_float(va[kk] << 16) * wa
                                 + __uint_as_float(vb[kk] << 16) * wb;
                acc[kk * 2 + 1] += __uint_as_float(va[kk] & 0xFFFF0000u) * wa
                                 + __uint_as_float(vb[kk] & 0xFFFF0000u) * wb;
            }
            ws += wa + wb;
        }
        // sum the 4 lane-group partials (lane ^16, ^32)
#pragma unroll
        for (int kk = 0; kk < 8; ++kk) {
            acc[kk] += __shfl_xor(acc[kk], 16);
            acc[kk] += __shfl_xor(acc[kk], 32);
        }
        ws += __shfl_xor(ws, 16);
        ws += __shfl_xor(ws, 32);
        float inv = 1.0f / fmaxf(ws, 1e-12f);
        if (grp == 0) {                          // 16 lanes x 16B = 256B row
            u32 o0 = pk2bf(acc[0] * inv, acc[1] * inv);
            u32 o1 = pk2bf(acc[2] * inv, acc[3] * inv);
            u32 o2 = pk2bf(acc[4] * inv, acc[5] * inv);
            u32 o3 = pk2bf(acc[6] * inv, acc[7] * inv);
            *(uint4*)(neigh + (size_t)node * D + l16 * 8) = make_uint4(o0, o1, o2, o3);
        }
    }
}

// ---------------------------------------------------------------------------
// Fused SAGE GEMM v3 — barrier-free streaming structure for tall-skinny shape.
// K=256 total, B = 128x256 bf16 = 64KB -> entire B lives in LDS (one barrier).
// Each wave owns 32 rows: whole A-slice loaded straight to registers.
// B is XOR-swizzled against the 16-way conflict of 512B-stride column reads.
// ---------------------------------------------------------------------------
template <bool NORM>
__global__ void __launch_bounds__(512, 2)
sage_gemm(const u16* __restrict__ axb,
          const u16* __restrict__ aneigh,
          const u16* __restrict__ Wb,      // [128][256] bf16
          const float* __restrict__ bias,  // [128]
          u16* __restrict__ outB,          // NORM=false
          float* __restrict__ outF,        // NORM=true
          int n) {
    __shared__ __attribute__((aligned(16))) char smem[65536];   // B, then out-stage

    const int tid  = threadIdx.x;
    const int wave = tid >> 6;
    const int lane = tid & 63;
    const int quad = lane >> 4;
    const int l16  = lane & 15;
    const int r0   = blockIdx.x * 256 + wave * 32;   // this wave's 32 rows

    // ---- A: 16 direct global->reg loads, whole K for two 16-row strips ----
    bf16x8 a[2][8];
    {
        int ra = r0 + l16;        if (ra >= n) ra = n - 1;   // clamp; never stored
        int rb = r0 + 16 + l16;   if (rb >= n) rb = n - 1;
        const u16* p00 = axb    + (size_t)ra * D + quad * 8;
        const u16* p10 = axb    + (size_t)rb * D + quad * 8;
        const u16* p01 = aneigh + (size_t)ra * D + quad * 8;
        const u16* p11 = aneigh + (size_t)rb * D + quad * 8;
#pragma unroll
        for (int kk = 0; kk < 4; ++kk) {
            a[0][kk] = *(const bf16x8*)(p00 + kk * 32);
            a[1][kk] = *(const bf16x8*)(p10 + kk * 32);
        }
#pragma unroll
        for (int kk = 0; kk < 4; ++kk) {
            a[0][4 + kk] = *(const bf16x8*)(p01 + kk * 32);
            a[1][4 + kk] = *(const bf16x8*)(p11 + kk * 32);
        }
    }

    // ---- stage whole B into LDS, XOR-swizzled, 64KB ----
#pragma unroll
    for (int it = 0; it < 8; ++it) {
        int e = it * 512 + tid;          // 4096 chunks = 128 cols x 32 k-chunks
        int c  = e >> 5;
        int kc = e & 31;
        uint4 v = *(const uint4*)(Wb + (size_t)c * 256 + kc * 8);
        u32 off = (((u32)c << 9) + ((u32)kc << 4)) ^ (((u32)c & 7u) << 4);
        *(uint4*)(smem + off) = v;
    }
    __syncthreads();                     // the ONLY barrier before the epilogue

    // ---- MFMA loop: consume A-regs in issue order (compiler counts vmcnt) ----
    f32x4 acc[2][8];
#pragma unroll
    for (int s = 0; s < 2; ++s)
#pragma unroll
        for (int c = 0; c < 8; ++c)
            acc[s][c] = (f32x4){0.f, 0.f, 0.f, 0.f};

#pragma unroll
    for (int kk = 0; kk < 8; ++kk) {
#pragma unroll
        for (int c = 0; c < 8; ++c) {
            u32 col = (u32)(c * 16 + l16);
            u32 off = ((col << 9) + ((u32)(kk * 4 + quad) << 4)) ^ ((col & 7u) << 4);
            bf16x8 b = *(const bf16x8*)(smem + off);
            acc[0][c] = __builtin_amdgcn_mfma_f32_16x16x32_bf16(a[0][kk], b, acc[0][c], 0, 0, 0);
            acc[1][c] = __builtin_amdgcn_mfma_f32_16x16x32_bf16(a[1][kk], b, acc[1][c], 0, 0, 0);
        }
    }

    __syncthreads();                     // B dead; smem reused for output staging

    // ---- Epilogue: C/D layout col=l16, row=quad*4+reg. Stage per-wave in
    // LDS, store fully coalesced 16B/lane. ----
    float bvals[8];
#pragma unroll
    for (int c = 0; c < 8; ++c) bvals[c] = bias[c * 16 + l16];

    if (NORM) {
        float* stg = (float*)smem + wave * 2048;     // 8KB per wave
#pragma unroll
        for (int s = 0; s < 2; ++s) {
#pragma unroll
            for (int reg = 0; reg < 4; ++reg) {
                float v[8];
#pragma unroll
                for (int c = 0; c < 8; ++c)
                    v[c] = fmaxf(acc[s][c][reg] + bvals[c], 0.0f);
                float ss = 0.f;
#pragma unroll
                for (int c = 0; c < 8; ++c) ss += v[c] * v[c];
                ss += __shfl_xor(ss, 1);
                ss += __shfl_xor(ss, 2);
                ss += __shfl_xor(ss, 4);
                ss += __shfl_xor(ss, 8);
                float inv = 1.0f / fmaxf(sqrtf(ss), 1e-12f);
#pragma unroll
                for (int c = 0; c < 8; ++c)
                    stg[(quad * 4 + reg) * 128 + c * 16 + l16] = v[c] * inv;
            }
#pragma unroll
            for (int p = 0; p < 8; ++p) {            // 16 rows x 512B, 2 rows/instr
                int lr = 2 * p + (lane >> 5);
                int grow = r0 + s * 16 + lr;
                float4 val = *(float4*)&stg[lr * 128 + (lane & 31) * 4];
                if (grow < n)
                    *(float4*)(outF + (size_t)grow * D + (lane & 31) * 4) = val;
            }
        }
    } else {
        u16* stg = (u16*)smem + wave * 2048;         // 4KB per wave
#pragma unroll
        for (int s = 0; s < 2; ++s) {
#pragma unroll
            for (int reg = 0; reg < 4; ++reg) {
#pragma unroll
                for (int c = 0; c < 8; ++c) {
                    float v = fmaxf(acc[s][c][reg] + bvals[c], 0.0f);
                    stg[(quad * 4 + reg) * 128 + c * 16 + l16] = f2bf(v);
                }
            }
#pragma unroll
            for (int p = 0; p < 4; ++p) {            // 16 rows x 256B, 4 rows/instr
                int lr = 4 * p + (lane >> 4);
                int grow = r0 + s * 16 + lr;
                uint4 val = *(uint4*)&stg[lr * 128 + l16 * 8];
                if (grow < n)
                    *(uint4*)(outB + (size_t)grow * D + l16 * 8) = val;
            }
        }
    }
}

extern "C" void kernel_launch(void* const* d_in, const int* in_sizes, int n_in,
                              void* d_out, int out_size, void* d_ws, size_t ws_size,
                              hipStream_t stream) {
    const float* x  = (const float*)d_in[0];
    const int*   ei = (const int*)d_in[1];   // [2, E]: row 0 = src, row 1 = dst
    const float* ew = (const float*)d_in[2];
    const float* W1 = (const float*)d_in[3];
    const float* b1 = (const float*)d_in[4];
    const float* W2 = (const float*)d_in[5];
    const float* b2 = (const float*)d_in[6];
    float* out = (float*)d_out;

    const int E = in_sizes[2];
    const int N = in_sizes[0] / D;
    const int nbuk = (N + BMASK) >> BSH;                 // 391 for N=100000
    const int CAP = ((2 * (E / nbuk + 1) + 1023) / 1024) * 1024;  // 4096

    const int* src = ei;
    const int* dst = ei + E;

    // workspace layout
    char* p = (char*)d_ws;
    auto alloc = [&](size_t bytes) { char* r = p; p += (bytes + 255) & ~(size_t)255; return r; };
    u16*   xb      = (u16*)  alloc((size_t)N * D * sizeof(u16));          // 25.6 MB
    u16*   hB      = (u16*)  alloc((size_t)N * D * sizeof(u16));          // 25.6 MB
    u16*   neighB  = (u16*)  alloc((size_t)N * D * sizeof(u16));          // 25.6 MB
    uint2* temp    = (uint2*)alloc(((size_t)nbuk * CAP + 64) * 8);        // 12.8 MB
    uint2* edge    = (uint2*)alloc(((size_t)nbuk * CAP + 64) * 8);        // 12.8 MB
    u16*   Wb1     = (u16*)  alloc((size_t)D * 2 * D * sizeof(u16));
    u16*   Wb2     = (u16*)  alloc((size_t)D * 2 * D * sizeof(u16));
    uint2* rowse   = (uint2*)alloc((size_t)N * sizeof(uint2));
    int*   bCursor = (int*)  alloc((size_t)(nbuk * CSTRIDE + 64) * sizeof(int));

    const int gemmGrid = (N + 255) / 256;
    const int n4 = N * D / 4;
    const int w4 = D * 2 * D / 4;   // 8192
    const int castTotal = n4 + 2 * w4;
    const int aggGrid = (N + 15) / 16;    // 4 nodes/wave x 4 waves/block

    // ---- casts + cursor init, then bucket partition + per-bucket CSR ----
    cast3_kernel    <<<(castTotal + 255) / 256, 256, 0, stream>>>(x, W1, W2, xb, Wb1, Wb2,
                                                                  n4, w4, bCursor, nbuk, CAP);
    partition_kernel<<<256, 1024, 0, stream>>>(src, dst, ew, bCursor, temp, E, nbuk);
    bucket_csr      <<<nbuk, 1024, 0, stream>>>(temp, bCursor, rowse, edge, N, CAP);

    // ---- Layer 1 ----
    aggregate_kernel<<<aggGrid, 256, 0, stream>>>(xb, rowse, edge, neighB, N);
    sage_gemm<false><<<gemmGrid, 512, 0, stream>>>(xb, neighB, Wb1, b1, hB, nullptr, N);

    // ---- Layer 2 (normalize fused into epilogue) ----
    aggregate_kernel<<<aggGrid, 256, 0, stream>>>(hB, rowse, edge, neighB, N);
    sage_gemm<true><<<gemmGrid, 512, 0, stream>>>(hB, neighB, Wb2, b2, nullptr, out, N);
}

// Round 11
// 250.145 us; speedup vs baseline: 1.0253x; 1.0253x over previous
//
#include <hip/hip_runtime.h>
#include <hip/hip_bf16.h>

#define D 128
#define BSH 8                      // 256 nodes per bucket
#define BMASK 255
#define CSTRIDE 32                 // bucket cursors padded to 1 per 128B line

typedef __attribute__((ext_vector_type(8))) short bf16x8;
typedef __attribute__((ext_vector_type(4))) float f32x4;
typedef unsigned short u16;
typedef unsigned int u32;

// fp32 -> bf16 RNE via gfx950 v_cvt_pk_bf16_f32 (1 VALU; VALUBusy 60->48
// confirmed r9). Same RNE rounding as the old bit-math.
__device__ inline u16 f2bf(float f) {
    u32 r;
    asm("v_cvt_pk_bf16_f32 %0, %1, %1" : "=v"(r) : "v"(f));
    return (u16)r;
}
// pack two f32 -> (bf16(lo) | bf16(hi)<<16) in one instruction
__device__ inline u32 pk2bf(float lo, float hi) {
    u32 r;
    asm("v_cvt_pk_bf16_f32 %0, %1, %2" : "=v"(r) : "v"(lo), "v"(hi));
    return r;
}

// ---------------------------------------------------------------------------
// fp32 -> bf16 cast of three arrays + bucket-cursor init, one launch.
// ---------------------------------------------------------------------------
__global__ void cast3_kernel(const float* __restrict__ a, const float* __restrict__ b,
                             const float* __restrict__ c, u16* __restrict__ oa,
                             u16* __restrict__ ob, u16* __restrict__ oc,
                             int na4, int nw4,
                             int* __restrict__ bCursor, int nbuk, int cap) {
    int i = blockIdx.x * blockDim.x + threadIdx.x;
    if (i < nbuk) bCursor[i * CSTRIDE] = i * cap;    // fixed-stride bucket bases
    const float* in; u16* out; int k;
    if (i < na4)                { in = a; out = oa; k = i; }
    else if (i < na4 + nw4)     { in = b; out = ob; k = i - na4; }
    else if (i < na4 + 2 * nw4) { in = c; out = oc; k = i - na4 - nw4; }
    else return;
    float4 v = *(const float4*)(in + (size_t)k * 4);
    *(uint2*)(out + (size_t)k * 4) = make_uint2(pk2bf(v.x, v.y), pk2bf(v.z, v.w));
}

// ---------------------------------------------------------------------------
// Partition edges into fixed-stride buckets (bucket b owns temp[b*cap ..)).
// 1024 threads/block (16 waves/CU) to cover strided-load latency.
// ---------------------------------------------------------------------------
__global__ void __launch_bounds__(1024)
partition_kernel(const int* __restrict__ src, const int* __restrict__ dst,
                 const float* __restrict__ w, int* __restrict__ bucketCursor,
                 uint2* __restrict__ temp, int E, int nbuk) {
    __shared__ int cnt[1024];
    __shared__ int base[1024];
    int per = (E + gridDim.x - 1) / gridDim.x;
    int lo = blockIdx.x * per;
    int hi = min(E, lo + per);
    for (int i = threadIdx.x; i < nbuk; i += blockDim.x) cnt[i] = 0;
    __syncthreads();
    for (int i = lo + threadIdx.x; i < hi; i += blockDim.x)
        atomicAdd(&cnt[src[i] >> BSH], 1);
    __syncthreads();
    for (int i = threadIdx.x; i < nbuk; i += blockDim.x)
        base[i] = cnt[i] ? atomicAdd(&bucketCursor[i * CSTRIDE], cnt[i]) : 0;
    __syncthreads();
    for (int i = threadIdx.x; i < nbuk; i += blockDim.x) cnt[i] = 0;
    __syncthreads();
    for (int i = lo + threadIdx.x; i < hi; i += blockDim.x) {
        int s = src[i];
        int b = s >> BSH;
        int off = atomicAdd(&cnt[b], 1);
        temp[base[b] + off] =
            make_uint2((u32)dst[i] | ((u32)(s & BMASK) << 17), __float_as_uint(w[i]));
    }
}

// ---------------------------------------------------------------------------
// Per-bucket CSR finalize. 1024 threads/block; scan sections guarded t<256.
// ---------------------------------------------------------------------------
__global__ void __launch_bounds__(1024)
bucket_csr(const uint2* __restrict__ temp, const int* __restrict__ bucketEnd,
           uint2* __restrict__ rowse, uint2* __restrict__ edge,
           int N, int cap) {
    int b = blockIdx.x;
    int lo = b * cap;
    int hi = bucketEnd[b * CSTRIDE];
    int t = threadIdx.x;
    __shared__ int deg_l[256];
    __shared__ int sc[256];
    __shared__ int cur[256];
    if (t < 256) deg_l[t] = 0;
    __syncthreads();
    for (int i = lo + t; i < hi; i += 1024)
        atomicAdd(&deg_l[temp[i].x >> 17], 1);
    __syncthreads();
    int mydeg = (t < 256) ? deg_l[t] : 0;
    if (t < 256) sc[t] = mydeg;
    __syncthreads();
    for (int off = 1; off < 256; off <<= 1) {
        int v = 0;
        if (t < 256 && t >= off) v = sc[t - off];
        __syncthreads();
        if (t < 256) sc[t] += v;
        __syncthreads();
    }
    if (t < 256) {
        int excl = (t == 0) ? 0 : sc[t - 1];
        int gnode = (b << BSH) + t;
        if (gnode < N) rowse[gnode] = make_uint2((u32)(lo + excl), (u32)mydeg);
        cur[t] = excl;
    }
    __syncthreads();
    for (int i = lo + t; i < hi; i += 1024) {
        uint2 r = temp[i];                     // L2-hot
        int p = atomicAdd(&cur[r.x >> 17], 1);
        edge[lo + p] = make_uint2(r.x & 0x1FFFFu, r.y);
    }
}

// ---------------------------------------------------------------------------
// Gather aggregation v4: lane-group gather (4 groups x 16 lanes, one VMEM
// covers 4 edges' 256B rows). Main loop is clamp-free (full 8-edge groups
// guaranteed in range); tail issues the second 4-slot gather only when
// needed (wave-uniform branch) — mean deg 8 meant ~44% of gathers were
// clamped duplicates before. Edge loads cached (NT regressed: r9 +5us,
// stream reuse within 128B lines lost).
// ---------------------------------------------------------------------------
__global__ void aggregate_kernel(const u16* __restrict__ feat,
                                 const uint2* __restrict__ rowse,
                                 const uint2* __restrict__ edge,
                                 u16* __restrict__ neigh, int n) {
    const char* fb = (const char*)feat;
    int wv   = blockIdx.x * 4 + (threadIdx.x >> 6);
    int lane = threadIdx.x & 63;
    int grp  = lane >> 4;          // edge slot within wave
    int l16  = lane & 15;          // owns dims l16*8 .. l16*8+7
    int node0 = wv * 4;
    if (node0 >= n) return;

    int begs[4], degs[4];
#pragma unroll
    for (int i = 0; i < 4; ++i) {
        int nd = node0 + i; if (nd > n - 1) nd = n - 1;
        uint2 se = rowse[nd];
        begs[i] = __builtin_amdgcn_readfirstlane((int)se.x);
        degs[i] = __builtin_amdgcn_readfirstlane((int)se.y);
    }

#pragma unroll 1
    for (int i = 0; i < 4; ++i) {
        int node = node0 + i;
        if (node >= n) break;
        int beg = begs[i];
        int end = beg + degs[i];
        float acc[8] = {0.f, 0.f, 0.f, 0.f, 0.f, 0.f, 0.f, 0.f};
        float ws = 0.f;
        int j = beg;
        // main loop: full 8-edge groups, no clamps (j+7 < end guaranteed)
        for (; j + 8 <= end; j += 8) {
            uint2 ea = edge[j + grp];
            uint2 eb = edge[j + 4 + grp];
            float wa = __uint_as_float(ea.y);
            float wb = __uint_as_float(eb.y);
            uint4 ua = *(const uint4*)(fb + (size_t)ea.x * 256u + (u32)l16 * 16u);
            uint4 ub = *(const uint4*)(fb + (size_t)eb.x * 256u + (u32)l16 * 16u);
            u32 va[4] = {ua.x, ua.y, ua.z, ua.w};
            u32 vb[4] = {ub.x, ub.y, ub.z, ub.w};
#pragma unroll
            for (int kk = 0; kk < 4; ++kk) {
                acc[kk * 2]     += __uint_as_float(va[kk] << 16) * wa
                                 + __uint_as_float(vb[kk] << 16) * wb;
                acc[kk * 2 + 1] += __uint_as_float(va[kk] & 0xFFFF0000u) * wa
                                 + __uint_as_float(vb[kk] & 0xFFFF0000u) * wb;
            }
            ws += wa + wb;
        }
        // tail: 1..7 edges remain; second 4-slot gather only if rem > 4
        if (j < end) {
            int ia = j + grp;
            int ca = ia < end ? ia : end - 1;
            uint2 ea = edge[ca];
            float wa = (ia < end) ? __uint_as_float(ea.y) : 0.f;
            uint4 ua = *(const uint4*)(fb + (size_t)ea.x * 256u + (u32)l16 * 16u);
            u32 va[4] = {ua.x, ua.y, ua.z, ua.w};
#pragma unroll
            for (int kk = 0; kk < 4; ++kk) {
                acc[kk * 2]     += __uint_as_float(va[kk] << 16) * wa;
                acc[kk * 2 + 1] += __uint_as_float(va[kk] & 0xFFFF0000u) * wa;
            }
            ws += wa;
            if (j + 4 < end) {                   // wave-uniform (end is scalar)
                int ib = j + 4 + grp;
                int cb = ib < end ? ib : end - 1;
                uint2 eb = edge[cb];
                float wb = (ib < end) ? __uint_as_float(eb.y) : 0.f;
                uint4 ub = *(const uint4*)(fb + (size_t)eb.x * 256u + (u32)l16 * 16u);
                u32 vb[4] = {ub.x, ub.y, ub.z, ub.w};
#pragma unroll
                for (int kk = 0; kk < 4; ++kk) {
                    acc[kk * 2]     += __uint_as_float(vb[kk] << 16) * wb;
                    acc[kk * 2 + 1] += __uint_as_float(vb[kk] & 0xFFFF0000u) * wb;
                }
                ws += wb;
            }
        }
        // sum the 4 lane-group partials (lane ^16, ^32)
#pragma unroll
        for (int kk = 0; kk < 8; ++kk) {
            acc[kk] += __shfl_xor(acc[kk], 16);
            acc[kk] += __shfl_xor(acc[kk], 32);
        }
        ws += __shfl_xor(ws, 16);
        ws += __shfl_xor(ws, 32);
        float inv = 1.0f / fmaxf(ws, 1e-12f);
        if (grp == 0) {                          // 16 lanes x 16B = 256B row
            u32 o0 = pk2bf(acc[0] * inv, acc[1] * inv);
            u32 o1 = pk2bf(acc[2] * inv, acc[3] * inv);
            u32 o2 = pk2bf(acc[4] * inv, acc[5] * inv);
            u32 o3 = pk2bf(acc[6] * inv, acc[7] * inv);
            *(uint4*)(neigh + (size_t)node * D + l16 * 8) = make_uint4(o0, o1, o2, o3);
        }
    }
}

// ---------------------------------------------------------------------------
// Fused SAGE GEMM v3 — barrier-free streaming structure for tall-skinny shape.
// K=256 total, B = 128x256 bf16 = 64KB -> entire B lives in LDS (one barrier).
// Each wave owns 32 rows: whole A-slice loaded straight to registers.
// B is XOR-swizzled against the 16-way conflict of 512B-stride column reads.
// ---------------------------------------------------------------------------
template <bool NORM>
__global__ void __launch_bounds__(512, 2)
sage_gemm(const u16* __restrict__ axb,
          const u16* __restrict__ aneigh,
          const u16* __restrict__ Wb,      // [128][256] bf16
          const float* __restrict__ bias,  // [128]
          u16* __restrict__ outB,          // NORM=false
          float* __restrict__ outF,        // NORM=true
          int n) {
    __shared__ __attribute__((aligned(16))) char smem[65536];   // B, then out-stage

    const int tid  = threadIdx.x;
    const int wave = tid >> 6;
    const int lane = tid & 63;
    const int quad = lane >> 4;
    const int l16  = lane & 15;
    const int r0   = blockIdx.x * 256 + wave * 32;   // this wave's 32 rows

    // ---- A: 16 direct global->reg loads, whole K for two 16-row strips ----
    bf16x8 a[2][8];
    {
        int ra = r0 + l16;        if (ra >= n) ra = n - 1;   // clamp; never stored
        int rb = r0 + 16 + l16;   if (rb >= n) rb = n - 1;
        const u16* p00 = axb    + (size_t)ra * D + quad * 8;
        const u16* p10 = axb    + (size_t)rb * D + quad * 8;
        const u16* p01 = aneigh + (size_t)ra * D + quad * 8;
        const u16* p11 = aneigh + (size_t)rb * D + quad * 8;
#pragma unroll
        for (int kk = 0; kk < 4; ++kk) {
            a[0][kk] = *(const bf16x8*)(p00 + kk * 32);
            a[1][kk] = *(const bf16x8*)(p10 + kk * 32);
        }
#pragma unroll
        for (int kk = 0; kk < 4; ++kk) {
            a[0][4 + kk] = *(const bf16x8*)(p01 + kk * 32);
            a[1][4 + kk] = *(const bf16x8*)(p11 + kk * 32);
        }
    }

    // ---- stage whole B into LDS, XOR-swizzled, 64KB ----
#pragma unroll
    for (int it = 0; it < 8; ++it) {
        int e = it * 512 + tid;          // 4096 chunks = 128 cols x 32 k-chunks
        int c  = e >> 5;
        int kc = e & 31;
        uint4 v = *(const uint4*)(Wb + (size_t)c * 256 + kc * 8);
        u32 off = (((u32)c << 9) + ((u32)kc << 4)) ^ (((u32)c & 7u) << 4);
        *(uint4*)(smem + off) = v;
    }
    __syncthreads();                     // the ONLY barrier before the epilogue

    // ---- MFMA loop: consume A-regs in issue order (compiler counts vmcnt) ----
    f32x4 acc[2][8];
#pragma unroll
    for (int s = 0; s < 2; ++s)
#pragma unroll
        for (int c = 0; c < 8; ++c)
            acc[s][c] = (f32x4){0.f, 0.f, 0.f, 0.f};

#pragma unroll
    for (int kk = 0; kk < 8; ++kk) {
#pragma unroll
        for (int c = 0; c < 8; ++c) {
            u32 col = (u32)(c * 16 + l16);
            u32 off = ((col << 9) + ((u32)(kk * 4 + quad) << 4)) ^ ((col & 7u) << 4);
            bf16x8 b = *(const bf16x8*)(smem + off);
            acc[0][c] = __builtin_amdgcn_mfma_f32_16x16x32_bf16(a[0][kk], b, acc[0][c], 0, 0, 0);
            acc[1][c] = __builtin_amdgcn_mfma_f32_16x16x32_bf16(a[1][kk], b, acc[1][c], 0, 0, 0);
        }
    }

    __syncthreads();                     // B dead; smem reused for output staging

    // ---- Epilogue: C/D layout col=l16, row=quad*4+reg. Stage per-wave in
    // LDS, store fully coalesced 16B/lane. ----
    float bvals[8];
#pragma unroll
    for (int c = 0; c < 8; ++c) bvals[c] = bias[c * 16 + l16];

    if (NORM) {
        float* stg = (float*)smem + wave * 2048;     // 8KB per wave
#pragma unroll
        for (int s = 0; s < 2; ++s) {
#pragma unroll
            for (int reg = 0; reg < 4; ++reg) {
                float v[8];
#pragma unroll
                for (int c = 0; c < 8; ++c)
                    v[c] = fmaxf(acc[s][c][reg] + bvals[c], 0.0f);
                float ss = 0.f;
#pragma unroll
                for (int c = 0; c < 8; ++c) ss += v[c] * v[c];
                ss += __shfl_xor(ss, 1);
                ss += __shfl_xor(ss, 2);
                ss += __shfl_xor(ss, 4);
                ss += __shfl_xor(ss, 8);
                float inv = 1.0f / fmaxf(sqrtf(ss), 1e-12f);
#pragma unroll
                for (int c = 0; c < 8; ++c)
                    stg[(quad * 4 + reg) * 128 + c * 16 + l16] = v[c] * inv;
            }
#pragma unroll
            for (int p = 0; p < 8; ++p) {            // 16 rows x 512B, 2 rows/instr
                int lr = 2 * p + (lane >> 5);
                int grow = r0 + s * 16 + lr;
                float4 val = *(float4*)&stg[lr * 128 + (lane & 31) * 4];
                if (grow < n)
                    *(float4*)(outF + (size_t)grow * D + (lane & 31) * 4) = val;
            }
        }
    } else {
        u16* stg = (u16*)smem + wave * 2048;         // 4KB per wave
#pragma unroll
        for (int s = 0; s < 2; ++s) {
#pragma unroll
            for (int reg = 0; reg < 4; ++reg) {
#pragma unroll
                for (int c = 0; c < 8; ++c) {
                    float v = fmaxf(acc[s][c][reg] + bvals[c], 0.0f);
                    stg[(quad * 4 + reg) * 128 + c * 16 + l16] = f2bf(v);
                }
            }
#pragma unroll
            for (int p = 0; p < 4; ++p) {            // 16 rows x 256B, 4 rows/instr
                int lr = 4 * p + (lane >> 4);
                int grow = r0 + s * 16 + lr;
                uint4 val = *(uint4*)&stg[lr * 128 + l16 * 8];
                if (grow < n)
                    *(uint4*)(outB + (size_t)grow * D + l16 * 8) = val;
            }
        }
    }
}

extern "C" void kernel_launch(void* const* d_in, const int* in_sizes, int n_in,
                              void* d_out, int out_size, void* d_ws, size_t ws_size,
                              hipStream_t stream) {
    const float* x  = (const float*)d_in[0];
    const int*   ei = (const int*)d_in[1];   // [2, E]: row 0 = src, row 1 = dst
    const float* ew = (const float*)d_in[2];
    const float* W1 = (const float*)d_in[3];
    const float* b1 = (const float*)d_in[4];
    const float* W2 = (const float*)d_in[5];
    const float* b2 = (const float*)d_in[6];
    float* out = (float*)d_out;

    const int E = in_sizes[2];
    const int N = in_sizes[0] / D;
    const int nbuk = (N + BMASK) >> BSH;                 // 391 for N=100000
    const int CAP = ((2 * (E / nbuk + 1) + 1023) / 1024) * 1024;  // 4096

    const int* src = ei;
    const int* dst = ei + E;

    // workspace layout
    char* p = (char*)d_ws;
    auto alloc = [&](size_t bytes) { char* r = p; p += (bytes + 255) & ~(size_t)255; return r; };
    u16*   xb      = (u16*)  alloc((size_t)N * D * sizeof(u16));          // 25.6 MB
    u16*   hB      = (u16*)  alloc((size_t)N * D * sizeof(u16));          // 25.6 MB
    u16*   neighB  = (u16*)  alloc((size_t)N * D * sizeof(u16));          // 25.6 MB
    uint2* temp    = (uint2*)alloc(((size_t)nbuk * CAP + 64) * 8);        // 12.8 MB
    uint2* edge    = (uint2*)alloc(((size_t)nbuk * CAP + 64) * 8);        // 12.8 MB
    u16*   Wb1     = (u16*)  alloc((size_t)D * 2 * D * sizeof(u16));
    u16*   Wb2     = (u16*)  alloc((size_t)D * 2 * D * sizeof(u16));
    uint2* rowse   = (uint2*)alloc((size_t)N * sizeof(uint2));
    int*   bCursor = (int*)  alloc((size_t)(nbuk * CSTRIDE + 64) * sizeof(int));

    const int gemmGrid = (N + 255) / 256;
    const int n4 = N * D / 4;
    const int w4 = D * 2 * D / 4;   // 8192
    const int castTotal = n4 + 2 * w4;
    const int aggGrid = (N + 15) / 16;    // 4 nodes/wave x 4 waves/block

    // ---- casts + cursor init, then bucket partition + per-bucket CSR ----
    cast3_kernel    <<<(castTotal + 255) / 256, 256, 0, stream>>>(x, W1, W2, xb, Wb1, Wb2,
                                                                  n4, w4, bCursor, nbuk, CAP);
    partition_kernel<<<256, 1024, 0, stream>>>(src, dst, ew, bCursor, temp, E, nbuk);
    bucket_csr      <<<nbuk, 1024, 0, stream>>>(temp, bCursor, rowse, edge, N, CAP);

    // ---- Layer 1 ----
    aggregate_kernel<<<aggGrid, 256, 0, stream>>>(xb, rowse, edge, neighB, N);
    sage_gemm<false><<<gemmGrid, 512, 0, stream>>>(xb, neighB, Wb1, b1, hB, nullptr, N);

    // ---- Layer 2 (normalize fused into epilogue) ----
    aggregate_kernel<<<aggGrid, 256, 0, stream>>>(hB, rowse, edge, neighB, N);
    sage_gemm<true><<<gemmGrid, 512, 0, stream>>>(hB, neighB, Wb2, b2, nullptr, out, N);
}